// Round 3
// baseline (130.204 us; speedup 1.0000x reference)
//
#include <hip/hip_runtime.h>
#include <stdint.h>

// BinarizedConv2d: out[d,h,w,o] = 1152 - 2*popcount(x_patch XOR w_filter)
// Per (tap,c) bit pair: 4xw - 2x - 2w + 1 == 1 - 2*(x^w); zero-padded x
// contributes 1-2w, matching the reference. Exact integers in fp32.
//
// V4: same two-dispatch structure as V3 (verified absmax=0, scratch in
// __device__ globals -- d_ws is poisoned 256 MiB/iter by the harness
// UNCONDITIONALLY (R2: fill persists with ws untouched), so only kernel
// time is controllable).
// Changes vs V3, from R2 analysis (pack+conv ~2x their traffic floor):
//   1. w-pack via float4: thread packs 4 o-words at once -> 4x fewer load
//      instructions (2.36M x 16B instead of 9.4M x 4B), uint4 result store.
//   2. x-pack gains COLUMN padding: g_xpk is [d][34][34] uint4 with rows
//      0,33 and cols 0,33 zeroed -> conv inner loop loses all boundary
//      cndmask selects (3 unconditional uniform loads per iw).

#define D_    64
#define H_    32
#define W_    32
#define CIN_  128
#define COUT_ 128
#define KK_   1152   // CIN * 3 * 3

#define XPK_N (D_ * 34 * 34)            // 73984 uint4 = 1,183,744 B
#define WPK_N (D_ * 36 * COUT_)         // 294912 words = 1,179,648 B

__device__ uint4    g_xpk[XPK_N];       // [d][row 0..33][col 0..33], pad = 0
__device__ unsigned g_wpk[WPK_N];       // [d][tap*4+k][o]

// ---------------------------------------------------------------------------
// Pack kernel: 1024 blocks x 256 threads, grid-stride over 3 independent jobs.
__global__ __launch_bounds__(256) void pack_kernel(const int* __restrict__ x,
                                                   const float* __restrict__ w) {
    int tid = blockIdx.x * 256 + threadIdx.x;
    int nth = gridDim.x * 256;

    // (a) zero pad entries: full rows 0,33 (34 cols each) + cols 0,33 of
    // rows 1..32. Jobs per d: 68 + 64 = 132.
    for (int t = tid; t < D_ * 132; t += nth) {
        int d = t / 132;
        int r = t % 132;
        int rr, cc;
        if (r < 68) { rr = (r >= 34) ? 33 : 0; cc = r % 34; }
        else        { int q = r - 68; rr = 1 + (q >> 1); cc = (q & 1) ? 33 : 0; }
        g_xpk[(d * 34 + rr) * 34 + cc] = make_uint4(0u, 0u, 0u, 0u);
    }

    // (b) x-pack: each wave packs 2 positions/iter via ballot.
    // Lanes 0-31 -> pos p chunk=lane, lanes 32-63 -> pos p+1 chunk=lane-32.
    // p even => p and p+1 always share (d,h), and c0 is even (<= 30).
    // Row h lives at padded row h+1; col c at padded col c+1.
    int lane   = threadIdx.x & 63;
    int wave   = tid >> 6;
    int nwaves = nth >> 6;
    for (int wt = wave; wt < (D_ * H_ * W_) / 2; wt += nwaves) {
        int p  = wt * 2;
        int d  = p >> 10;
        int h  = (p >> 5) & 31;
        int c0 = p & 31;
        const int* xp = x + (long)p * CIN_ + ((lane >> 5) ? CIN_ : 0);
        int4 v = ((const int4*)xp)[lane & 31];
        unsigned long long b0 = __ballot(v.x != 0);
        unsigned long long b1 = __ballot(v.y != 0);
        unsigned long long b2 = __ballot(v.z != 0);
        unsigned long long b3 = __ballot(v.w != 0);
        long base = ((long)d * 34 + h + 1) * 34;
        if (lane == 0)
            g_xpk[base + c0 + 1] =
                make_uint4((unsigned)b0, (unsigned)b1, (unsigned)b2, (unsigned)b3);
        else if (lane == 32)
            g_xpk[base + c0 + 2] =
                make_uint4((unsigned)(b0 >> 32), (unsigned)(b1 >> 32),
                           (unsigned)(b2 >> 32), (unsigned)(b3 >> 32));
    }

    // (c) w-pack, float4 form: thread t packs the 4 words (d, rest, o4*4..+3).
    // For fixed j, each 32-lane half reads 512 B contiguous (one channel row).
    // Each w element read exactly once; result stored as one uint4.
    for (int t = tid; t < WPK_N / 4; t += nth) {
        int o4   = t & 31;
        int dr   = t >> 5;           // d*36 + rest
        int rest = dr % 36;          // tap*4 + k
        int d    = dr / 36;
        int tap  = rest >> 2;
        int k    = rest & 3;
        const float* wp = w + ((long)d * 9 + tap) * (CIN_ * COUT_) + o4 * 4;
        unsigned m0 = 0, m1 = 0, m2 = 0, m3 = 0;
#pragma unroll
        for (int j = 0; j < 32; ++j) {
            float4 v = *(const float4*)(wp + (long)(4 * j + k) * COUT_);
            if (v.x != 0.f) m0 |= 1u << j;
            if (v.y != 0.f) m1 |= 1u << j;
            if (v.z != 0.f) m2 |= 1u << j;
            if (v.w != 0.f) m3 |= 1u << j;
        }
        *(uint4*)&g_wpk[((long)dr << 7) + o4 * 4] = make_uint4(m0, m1, m2, m3);
    }
}

// ---------------------------------------------------------------------------
// Compute kernel: block = (d = bid>>5, h = bid&31), thread = o. 32 outputs
// per thread along w. Zero LDS, zero barriers, zero boundary branches.
__global__ __launch_bounds__(128) void conv_kernel(float* __restrict__ out) {
    int bid = blockIdx.x;
    int d   = bid >> 5;
    int h   = bid & 31;
    int o   = threadIdx.x;

    // 36 coalesced w-word loads -> wv[tap] components = k 0..3
    const unsigned* wb = g_wpk + (long)d * 36 * COUT_ + o;
    uint4 wv[9];
#pragma unroll
    for (int t = 0; t < 9; ++t) {
        wv[t].x = wb[(t * 4 + 0) * COUT_];
        wv[t].y = wb[(t * 4 + 1) * COUT_];
        wv[t].z = wb[(t * 4 + 2) * COUT_];
        wv[t].w = wb[(t * 4 + 3) * COUT_];
    }

    // padded rows h-1,h,h+1 of this d live at xp[0], xp[34], xp[68]
    const uint4* xp = g_xpk + ((long)d * 34 + h) * 34;
    float* op = out + ((long)(d * H_ + h) * W_) * COUT_ + o;

    // Sliding 3-col register window over padded cols; output col iw uses
    // padded cols iw, iw+1, iw+2 (max 33). All loads unconditional.
    uint4 ca[3], cb[3], cc_[3];
#pragma unroll
    for (int i = 0; i < 3; ++i) {
        ca[i] = xp[i * 34 + 0];      // zero pad col
        cb[i] = xp[i * 34 + 1];      // real col 0
    }

#pragma unroll
    for (int iw = 0; iw < W_; ++iw) {
#pragma unroll
        for (int i = 0; i < 3; ++i) cc_[i] = xp[i * 34 + iw + 2];
        int pop = 0;
#pragma unroll
        for (int i = 0; i < 3; ++i) {
            uint4 xa;
            uint4 w0 = wv[i * 3 + 0], w1 = wv[i * 3 + 1], w2 = wv[i * 3 + 2];
            xa = ca[i];
            pop += __popc(xa.x ^ w0.x) + __popc(xa.y ^ w0.y)
                 + __popc(xa.z ^ w0.z) + __popc(xa.w ^ w0.w);
            xa = cb[i];
            pop += __popc(xa.x ^ w1.x) + __popc(xa.y ^ w1.y)
                 + __popc(xa.z ^ w1.z) + __popc(xa.w ^ w1.w);
            xa = cc_[i];
            pop += __popc(xa.x ^ w2.x) + __popc(xa.y ^ w2.y)
                 + __popc(xa.z ^ w2.z) + __popc(xa.w ^ w2.w);
        }
        op[(long)iw * COUT_] = (float)(KK_ - 2 * pop);
#pragma unroll
        for (int i = 0; i < 3; ++i) { ca[i] = cb[i]; cb[i] = cc_[i]; }
    }
}

// ---------------------------------------------------------------------------
extern "C" void kernel_launch(void* const* d_in, const int* in_sizes, int n_in,
                              void* d_out, int out_size, void* d_ws, size_t ws_size,
                              hipStream_t stream) {
    const int*   x   = (const int*)d_in[0];    // bool -> int32 0/1 (verified R1)
    const float* w   = (const float*)d_in[1];  // float32 0/1
    float*       out = (float*)d_out;
    (void)d_ws; (void)ws_size;                 // untouched; harness poisons it
                                               // unconditionally (R2 finding)

    pack_kernel<<<1024, 256, 0, stream>>>(x, w);
    conv_kernel<<<2048, 128, 0, stream>>>(out);
}